// Round 8
// baseline (215.469 us; speedup 1.0000x reference)
//
#include <hip/hip_runtime.h>
#include <hip/hip_fp16.h>
#include <cstdint>

#define SEQ 4096
#define DIM 1024

typedef _Float16 f16x8 __attribute__((ext_vector_type(8)));
typedef float f32x16 __attribute__((ext_vector_type(16)));
typedef __attribute__((address_space(1))) void as1_void;
typedef __attribute__((address_space(3))) void as3_void;

__device__ __forceinline__ ushort f2h(float f) {
  _Float16 h = (_Float16)f;
  return __builtin_bit_cast(ushort, h);
}

// ---------------- fused conversions: z<3 -> W transpose+cvt, z==3 -> X cvt ----------------
__global__ void convert_all_kernel(const float* __restrict__ X, const float* __restrict__ Wk,
                                   const float* __restrict__ Wv, const float* __restrict__ Wq,
                                   ushort* __restrict__ Xh, ushort* __restrict__ Wt) {
  const int z = blockIdx.z;
  const int tx = threadIdx.x, ty = threadIdx.y;  // (32,8)
  if (z == 3) {
    const int bid = blockIdx.y * 32 + blockIdx.x;
    const int t = ty * 32 + tx;
#pragma unroll
    for (int k = 0; k < 4; k++) {
      int i = bid * 1024 + k * 256 + t;
      float4 v = reinterpret_cast<const float4*>(X)[i];
      ushort4 o = { f2h(v.x), f2h(v.y), f2h(v.z), f2h(v.w) };
      reinterpret_cast<ushort4*>(Xh)[i] = o;
    }
    return;
  }
  __shared__ float tile[32][33];
  const float* W = (z == 0) ? Wk : (z == 1) ? Wv : Wq;
  int n0 = blockIdx.x * 32, k0 = blockIdx.y * 32;
#pragma unroll
  for (int r = 0; r < 4; r++) {
    int k = ty + r * 8;
    tile[k][tx] = W[(size_t)(k0 + k) * DIM + n0 + tx];
  }
  __syncthreads();
  ushort* out = Wt + (size_t)z * DIM * DIM;
#pragma unroll
  for (int r = 0; r < 4; r++) {
    int n = ty + r * 8;
    out[(size_t)(n0 + n) * DIM + k0 + tx] = f2h(tile[tx][n]);
  }
}

// ---------------- core GEMM: 256 threads, 4 waves (one/SIMD), 256x256 tile ----------------
// Each wave owns a 128x128 subtile: 4x4 fragments of 32x32x16 MFMA, acc = 256 regs
// (unified VGPR/AGPR file, 1 wave/SIMD => 512-reg budget, __launch_bounds__(256,1)).
// Rationale (R7 post-mortem): LDS read pipe was the binding resource. 4x4 frags
// read 8 b128 per 16 MFMA (0.5/MFMA vs 0.75 before): CU-iter LDS = 128KB read +
// 64KB staging write (~1700 cyc) < MFMA 2066 cyc => matrix pipe becomes critical.
// Double-buffered staging: loads(it+1) issued right after the barrier, fly during
// compute(it) (~2066 cyc window > ~1400 cyc L2 service+latency).
// XOR chunk swizzle key(r)=(r&7)^((r>>3)&3); 0 bank conflicts verified R4-R7.
__device__ __forceinline__ void gemm256(const ushort* __restrict__ A,
                                        const ushort* __restrict__ B,
                                        ushort* __restrict__ C,
                                        int N, int K, int m0, int n0,
                                        int kt0, int ktend) {
  constexpr int BK = 64;
  __shared__ __align__(16) ushort As[2][256 * BK];  // 2 x 32 KB
  __shared__ __align__(16) ushort Bs[2][256 * BK];  // 2 x 32 KB
  const int tid = threadIdx.x;            // [0,256)
  const int wave = tid >> 6, lane = tid & 63;
  const int l31 = lane & 31, khalf = lane >> 5;
  const int wm = (wave & 1) * 128, wn = (wave >> 1) * 128;

  const int srow = tid >> 3;              // [0,32)
  const int skey = (srow & 7) ^ ((srow >> 3) & 3);
  const int sce = (((tid & 7) ^ skey) * 8);
  const int rk = (l31 & 7) ^ ((l31 >> 3) & 3);

  const ushort* Abase = A + (size_t)(m0 + srow) * K + sce;
  const ushort* Bbase = B + (size_t)(n0 + srow) * K + sce;

  f32x16 acc[4][4];
#pragma unroll
  for (int i = 0; i < 4; i++)
#pragma unroll
    for (int j = 0; j < 4; j++)
#pragma unroll
      for (int r = 0; r < 16; r++) acc[i][j][r] = 0.f;

  const int niter = (ktend - kt0) / BK;

  // prefetch iter 0 into buffer 0 (each wave stages 8 rows per q-step: rows q*32 + wave*8 + lane/8)
#pragma unroll
  for (int q = 0; q < 8; q++) {
    __builtin_amdgcn_global_load_lds((const as1_void*)(Abase + (size_t)q * 32 * K + kt0),
                                     (as3_void*)&As[0][wave * 512 + q * 2048], 16, 0, 0);
    __builtin_amdgcn_global_load_lds((const as1_void*)(Bbase + (size_t)q * 32 * K + kt0),
                                     (as3_void*)&Bs[0][wave * 512 + q * 2048], 16, 0, 0);
  }

  for (int it = 0; it < niter; ++it) {
    __syncthreads();  // drains loads(it) issued one iter ago
    if (it + 1 < niter) {
      const int kt = kt0 + (it + 1) * BK;
      const int nb = (it + 1) & 1;
#pragma unroll
      for (int q = 0; q < 8; q++) {
        __builtin_amdgcn_global_load_lds((const as1_void*)(Abase + (size_t)q * 32 * K + kt),
                                         (as3_void*)&As[nb][wave * 512 + q * 2048], 16, 0, 0);
        __builtin_amdgcn_global_load_lds((const as1_void*)(Bbase + (size_t)q * 32 * K + kt),
                                         (as3_void*)&Bs[nb][wave * 512 + q * 2048], 16, 0, 0);
      }
    }
    const int cb = it & 1;
#pragma unroll
    for (int ks = 0; ks < 4; ks++) {
      f16x8 af[4], bfr[4];
      const int co = ((ks * 2 + khalf) ^ rk) * 8;
#pragma unroll
      for (int i = 0; i < 4; i++)
        af[i] = *reinterpret_cast<const f16x8*>(&As[cb][(wm + i * 32 + l31) * BK + co]);
#pragma unroll
      for (int j = 0; j < 4; j++)
        bfr[j] = *reinterpret_cast<const f16x8*>(&Bs[cb][(wn + j * 32 + l31) * BK + co]);
#pragma unroll
      for (int i = 0; i < 4; i++)
#pragma unroll
        for (int j = 0; j < 4; j++)
          acc[i][j] = __builtin_amdgcn_mfma_f32_32x32x16_f16(af[i], bfr[j], acc[i][j], 0, 0, 0);
    }
  }

  // epilogue: 32x32 C/D layout col=lane&31, row=(reg&3)+8*(reg>>2)+4*(lane>>5)  [m74/m101]
#pragma unroll
  for (int i = 0; i < 4; i++)
#pragma unroll
    for (int j = 0; j < 4; j++)
#pragma unroll
      for (int r = 0; r < 16; r++) {
        int row = m0 + wm + i * 32 + (r & 3) + 8 * (r >> 2) + 4 * khalf;
        int col = n0 + wn + j * 32 + l31;
        C[(size_t)row * N + col] = f2h(acc[i][j][r]);
      }
}

// ---------------- fused K/Q/V^T projections (192 blocks) ----------------
__global__ __launch_bounds__(256, 1) void proj_kernel(const ushort* __restrict__ Xh,
                                                      const ushort* __restrict__ Wt,
                                                      ushort* __restrict__ Kh,
                                                      ushort* __restrict__ Qh,
                                                      ushort* __restrict__ Vt) {
  const int z = blockIdx.z;
  const int bx = blockIdx.x;  // [0,64)
  if (z < 2) {
    const ushort* B = Wt + (size_t)(z == 0 ? 0 : 2) * DIM * DIM;
    ushort* C = (z == 0) ? Kh : Qh;
    gemm256(Xh, B, C, DIM, DIM, (bx >> 2) * 256, (bx & 3) * 256, 0, DIM);
  } else {
    gemm256(Wt + (size_t)DIM * DIM, Xh, Vt, SEQ, DIM,
            (bx >> 4) * 256, (bx & 15) * 256, 0, DIM);
  }
}

// ---------------- S = K @ Q^T (fp16), 256x256 tiles, XCD-chunked ----------------
__global__ __launch_bounds__(256, 1) void score_kernel(const ushort* __restrict__ Kh,
                                                       const ushort* __restrict__ Qh,
                                                       ushort* __restrict__ S) {
  const int f = blockIdx.x;           // [0,256)
  const int xcd = f & 7;
  const int r = f >> 3;               // [0,32)
  const int g = xcd * 2 + (r >> 4);   // 4x4 supertile index [0,16)
  const int w = r & 15;
  const int sx = w & 3, sy = w >> 2;
  const int tx = (g & 3) * 4 + sx;    // [0,16)
  const int ty = (g >> 2) * 4 + sy;   // [0,16)
  gemm256(Kh, Qh, S, SEQ, DIM, ty * 256, tx * 256, 0, DIM);
}

// ---------------- O partials: split-K=4, 256x256 tiles, fp16 ----------------
__global__ __launch_bounds__(256, 1) void out_splitk_kernel(const ushort* __restrict__ P,
                                                            const ushort* __restrict__ Vt,
                                                            ushort* __restrict__ Part) {
  const int f = blockIdx.x;           // [0,256)
  const int xcd = f & 7;
  const int r = f >> 3;               // [0,32)
  const int z = r >> 3;               // split slice [0,4)
  const int u = r & 7;
  const int t = xcd * 8 + u;          // [0,64)
  const int ty = t >> 2, tx = t & 3;  // 16 x 4 tiles
  ushort* C = Part + (size_t)z * SEQ * DIM;
  gemm256(P, Vt, C, DIM, SEQ, ty * 256, tx * 256,
          z * (SEQ / 4), (z + 1) * (SEQ / 4));
}

__global__ void reduce4_kernel(const ushort* __restrict__ Part, float* __restrict__ out, int n8) {
  int i = blockIdx.x * blockDim.x + threadIdx.x;
  if (i >= n8) return;
  const f16x8* p0 = reinterpret_cast<const f16x8*>(Part);
  const f16x8* p1 = p0 + n8;
  const f16x8* p2 = p1 + n8;
  const f16x8* p3 = p2 + n8;
  f16x8 a = p0[i], b = p1[i], c = p2[i], d = p3[i];
  float4 lo, hi;
  lo.x = (float)a[0] + (float)b[0] + (float)c[0] + (float)d[0];
  lo.y = (float)a[1] + (float)b[1] + (float)c[1] + (float)d[1];
  lo.z = (float)a[2] + (float)b[2] + (float)c[2] + (float)d[2];
  lo.w = (float)a[3] + (float)b[3] + (float)c[3] + (float)d[3];
  hi.x = (float)a[4] + (float)b[4] + (float)c[4] + (float)d[4];
  hi.y = (float)a[5] + (float)b[5] + (float)c[5] + (float)d[5];
  hi.z = (float)a[6] + (float)b[6] + (float)c[6] + (float)d[6];
  hi.w = (float)a[7] + (float)b[7] + (float)c[7] + (float)d[7];
  reinterpret_cast<float4*>(out)[i * 2] = lo;
  reinterpret_cast<float4*>(out)[i * 2 + 1] = hi;
}

// ---------------- row softmax: one wave per row ----------------
__global__ __launch_bounds__(256) void softmax_kernel(const ushort* __restrict__ S,
                                                      ushort* __restrict__ P) {
  const int wave = threadIdx.x >> 6, lane = threadIdx.x & 63;
  const int row = blockIdx.x * 4 + wave;
  const ushort* s = S + (size_t)row * SEQ;
  float v[64];
#pragma unroll
  for (int i = 0; i < 8; i++) {
    f16x8 h = reinterpret_cast<const f16x8*>(s)[i * 64 + lane];
#pragma unroll
    for (int j = 0; j < 8; j++) v[i * 8 + j] = (float)h[j];
  }
  float m = v[0];
#pragma unroll
  for (int j = 1; j < 64; j++) m = fmaxf(m, v[j]);
#pragma unroll
  for (int o = 32; o > 0; o >>= 1) m = fmaxf(m, __shfl_xor(m, o, 64));
  float sum = 0.f;
#pragma unroll
  for (int j = 0; j < 64; j++) {
    v[j] = __expf(v[j] - m);
    sum += v[j];
  }
#pragma unroll
  for (int o = 32; o > 0; o >>= 1) sum += __shfl_xor(sum, o, 64);
  float inv = 1.0f / sum;
  ushort* p = P + (size_t)row * SEQ;
#pragma unroll
  for (int i = 0; i < 8; i++) {
    f16x8 h;
#pragma unroll
    for (int j = 0; j < 8; j++) h[j] = (_Float16)(v[i * 8 + j] * inv);
    reinterpret_cast<f16x8*>(p)[i * 64 + lane] = h;
  }
}

extern "C" void kernel_launch(void* const* d_in, const int* in_sizes, int n_in,
                              void* d_out, int out_size, void* d_ws, size_t ws_size,
                              hipStream_t stream) {
  const float* X = (const float*)d_in[0];
  const float* Wk = (const float*)d_in[1];
  const float* Wv = (const float*)d_in[2];
  const float* Wq = (const float*)d_in[3];

  char* ws = (char*)d_ws;
  size_t off = 0;
  ushort* Xh = (ushort*)(ws + off); off += (size_t)SEQ * DIM * 2;      // 8 MB
  ushort* Wt = (ushort*)(ws + off); off += (size_t)3 * DIM * DIM * 2;  // 6 MB
  ushort* Kh = (ushort*)(ws + off); off += (size_t)SEQ * DIM * 2;      // 8 MB
  ushort* Qh = (ushort*)(ws + off); off += (size_t)SEQ * DIM * 2;      // 8 MB
  ushort* Vt = (ushort*)(ws + off); off += (size_t)SEQ * DIM * 2;      // 8 MB
  ushort* S = (ushort*)(ws + off);  off += (size_t)SEQ * SEQ * 2;      // 32 MB (reused as partials)
  ushort* P = (ushort*)(ws + off);  off += (size_t)SEQ * SEQ * 2;      // 32 MB

  ushort* Part = S;  // 4 x [SEQ,DIM] fp16 partials alias S; S dead after softmax

  convert_all_kernel<<<dim3(32, 32, 4), dim3(32, 8), 0, stream>>>(X, Wk, Wv, Wq, Xh, Wt);
  proj_kernel<<<dim3(64, 1, 3), 256, 0, stream>>>(Xh, Wt, Kh, Qh, Vt);
  score_kernel<<<256, 256, 0, stream>>>(Kh, Qh, S);
  softmax_kernel<<<1024, 256, 0, stream>>>(S, P);
  out_splitk_kernel<<<256, 256, 0, stream>>>(P, Vt, Part);
  reduce4_kernel<<<SEQ * DIM / 8 / 256, 256, 0, stream>>>(Part, (float*)d_out, SEQ * DIM / 8);
}

// Round 9
// 214.685 us; speedup vs baseline: 1.0037x; 1.0037x over previous
//
#include <hip/hip_runtime.h>
#include <hip/hip_fp16.h>
#include <cstdint>

#define SEQ 4096
#define DIM 1024

typedef _Float16 f16x8 __attribute__((ext_vector_type(8)));
typedef float f32x16 __attribute__((ext_vector_type(16)));
typedef __attribute__((address_space(1))) void as1_void;
typedef __attribute__((address_space(3))) void as3_void;

__device__ __forceinline__ ushort f2h(float f) {
  _Float16 h = (_Float16)f;
  return __builtin_bit_cast(ushort, h);
}

// ---------------- fused conversions: z<3 -> W transpose+cvt, z==3 -> X cvt ----------------
__global__ void convert_all_kernel(const float* __restrict__ X, const float* __restrict__ Wk,
                                   const float* __restrict__ Wv, const float* __restrict__ Wq,
                                   ushort* __restrict__ Xh, ushort* __restrict__ Wt) {
  const int z = blockIdx.z;
  const int tx = threadIdx.x, ty = threadIdx.y;  // (32,8)
  if (z == 3) {
    const int bid = blockIdx.y * 32 + blockIdx.x;
    const int t = ty * 32 + tx;
#pragma unroll
    for (int k = 0; k < 4; k++) {
      int i = bid * 1024 + k * 256 + t;
      float4 v = reinterpret_cast<const float4*>(X)[i];
      ushort4 o = { f2h(v.x), f2h(v.y), f2h(v.z), f2h(v.w) };
      reinterpret_cast<ushort4*>(Xh)[i] = o;
    }
    return;
  }
  __shared__ float tile[32][33];
  const float* W = (z == 0) ? Wk : (z == 1) ? Wv : Wq;
  int n0 = blockIdx.x * 32, k0 = blockIdx.y * 32;
#pragma unroll
  for (int r = 0; r < 4; r++) {
    int k = ty + r * 8;
    tile[k][tx] = W[(size_t)(k0 + k) * DIM + n0 + tx];
  }
  __syncthreads();
  ushort* out = Wt + (size_t)z * DIM * DIM;
#pragma unroll
  for (int r = 0; r < 4; r++) {
    int n = ty + r * 8;
    out[(size_t)(n0 + n) * DIM + k0 + tx] = f2h(tile[tx][n]);
  }
}

// ---------------- core GEMM: 128 threads (2 waves), 128x128 tile, 64x128/wave ----------------
// R8 post-mortem: in-block dbuf is dead (compiler drains vmcnt at every barrier);
// overlap must come from OTHER resident blocks. This geometry keeps the proven
// 64x128 wave tile (2x4 frags of 32x32x16, LDS-read/MFMA = 1.11, acc 128 VGPR)
// but shrinks the barrier domain to 2 waves and fits 4 blocks/CU (32 KB LDS,
// ~185 VGPR -> 2 waves/SIMD): 4 staggered stage/compute phases per CU.
// XOR chunk swizzle key(r) = (r&7)^((r>>3)&3); staging key recomputed per q
// (row stride 16); read-side key invariant under +32/+64 offsets. 0 conflicts R4-R8.
__device__ __forceinline__ void gemm128(const ushort* __restrict__ A,
                                        const ushort* __restrict__ B,
                                        ushort* __restrict__ C,
                                        int N, int K, int m0, int n0,
                                        int kt0, int ktend) {
  constexpr int BK = 64;
  __shared__ __align__(16) ushort As[128 * BK];  // 16 KB
  __shared__ __align__(16) ushort Bs[128 * BK];  // 16 KB
  const int tid = threadIdx.x;            // [0,128)
  const int wave = tid >> 6, lane = tid & 63;
  const int l31 = lane & 31, khalf = lane >> 5;
  const int wm = wave * 64;               // wave's m-offset; n spans full 128

  const int srow = tid >> 3;              // [0,16) block-wide row within a q-step
  const int rk = (l31 & 7) ^ ((l31 >> 3) & 3);

  f32x16 acc[2][4];
#pragma unroll
  for (int i = 0; i < 2; i++)
#pragma unroll
    for (int j = 0; j < 4; j++)
#pragma unroll
      for (int r = 0; r < 16; r++) acc[i][j][r] = 0.f;

  for (int kt = kt0; kt < ktend; kt += BK) {
    __syncthreads();  // previous compute done before LDS overwrite
#pragma unroll
    for (int q = 0; q < 8; q++) {
      const int row = q * 16 + srow;
      const int key = (row & 7) ^ ((row >> 3) & 3);
      const int ce = ((tid & 7) ^ key) * 8;
      __builtin_amdgcn_global_load_lds((const as1_void*)(A + (size_t)(m0 + row) * K + kt + ce),
                                       (as3_void*)&As[q * 1024 + wave * 512], 16, 0, 0);
    }
#pragma unroll
    for (int q = 0; q < 8; q++) {
      const int row = q * 16 + srow;
      const int key = (row & 7) ^ ((row >> 3) & 3);
      const int ce = ((tid & 7) ^ key) * 8;
      __builtin_amdgcn_global_load_lds((const as1_void*)(B + (size_t)(n0 + row) * K + kt + ce),
                                       (as3_void*)&Bs[q * 1024 + wave * 512], 16, 0, 0);
    }
    __syncthreads();  // staging visible
#pragma unroll
    for (int ks = 0; ks < 4; ks++) {
      f16x8 af[2], bfr[4];
      const int co = ((ks * 2 + khalf) ^ rk) * 8;
#pragma unroll
      for (int i = 0; i < 2; i++)
        af[i] = *reinterpret_cast<const f16x8*>(&As[(wm + i * 32 + l31) * BK + co]);
#pragma unroll
      for (int j = 0; j < 4; j++)
        bfr[j] = *reinterpret_cast<const f16x8*>(&Bs[(j * 32 + l31) * BK + co]);
#pragma unroll
      for (int i = 0; i < 2; i++)
#pragma unroll
        for (int j = 0; j < 4; j++)
          acc[i][j] = __builtin_amdgcn_mfma_f32_32x32x16_f16(af[i], bfr[j], acc[i][j], 0, 0, 0);
    }
  }

  // epilogue: 32x32 C/D layout col=lane&31, row=(reg&3)+8*(reg>>2)+4*(lane>>5)  [m74/m101]
#pragma unroll
  for (int i = 0; i < 2; i++)
#pragma unroll
    for (int j = 0; j < 4; j++)
#pragma unroll
      for (int r = 0; r < 16; r++) {
        int row = m0 + wm + i * 32 + (r & 3) + 8 * (r >> 2) + 4 * khalf;
        int col = n0 + j * 32 + l31;
        C[(size_t)row * N + col] = f2h(acc[i][j][r]);
      }
}

// ---------------- fused K/Q/V^T projections (768 blocks, 128 thr) ----------------
__global__ __launch_bounds__(128, 2) void proj_kernel(const ushort* __restrict__ Xh,
                                                      const ushort* __restrict__ Wt,
                                                      ushort* __restrict__ Kh,
                                                      ushort* __restrict__ Qh,
                                                      ushort* __restrict__ Vt) {
  const int z = blockIdx.z;
  const int bx = blockIdx.x;  // [0,256)
  if (z < 2) {
    const ushort* B = Wt + (size_t)(z == 0 ? 0 : 2) * DIM * DIM;
    ushort* C = (z == 0) ? Kh : Qh;
    gemm128(Xh, B, C, DIM, DIM, (bx >> 3) * 128, (bx & 7) * 128, 0, DIM);
  } else {
    gemm128(Wt + (size_t)DIM * DIM, Xh, Vt, SEQ, DIM,
            (bx >> 5) * 128, (bx & 31) * 128, 0, DIM);
  }
}

// ---------------- S = K @ Q^T (fp16), 128x128 tiles, XCD-swizzled 8x8 supertiles ----------------
__global__ __launch_bounds__(128, 2) void score_kernel(const ushort* __restrict__ Kh,
                                                       const ushort* __restrict__ Qh,
                                                       ushort* __restrict__ S) {
  const int f = blockIdx.x;          // [0,1024)
  const int xcd = f & 7;
  const int r = f >> 3;              // [0,128)
  const int t = xcd * 128 + r;       // XCD-contiguous
  const int st = t >> 6, within = t & 63;
  const int sx = within & 7, sy = within >> 3;
  const int tx = (st & 3) * 8 + sx;  // [0,32)
  const int ty = (st >> 2) * 8 + sy; // [0,32)
  gemm128(Kh, Qh, S, SEQ, DIM, ty * 128, tx * 128, 0, DIM);
}

// ---------------- O partials: split-K=4, 128x128 tiles, fp16, XCD-swizzled ----------------
__global__ __launch_bounds__(128, 2) void out_splitk_kernel(const ushort* __restrict__ P,
                                                            const ushort* __restrict__ Vt,
                                                            ushort* __restrict__ Part) {
  const int f = blockIdx.x;          // [0,1024)
  const int z = f >> 8;              // split slice
  const int q = f & 255;
  const int xcd = q & 7;
  const int r = q >> 3;              // [0,32)
  const int t = xcd * 32 + r;        // [0,256): 32m x 8n tiles
  const int ty = t >> 3, tx = t & 7;
  ushort* C = Part + (size_t)z * SEQ * DIM;
  gemm128(P, Vt, C, DIM, SEQ, ty * 128, tx * 128,
          z * (SEQ / 4), (z + 1) * (SEQ / 4));
}

__global__ void reduce4_kernel(const ushort* __restrict__ Part, float* __restrict__ out, int n8) {
  int i = blockIdx.x * blockDim.x + threadIdx.x;
  if (i >= n8) return;
  const f16x8* p0 = reinterpret_cast<const f16x8*>(Part);
  const f16x8* p1 = p0 + n8;
  const f16x8* p2 = p1 + n8;
  const f16x8* p3 = p2 + n8;
  f16x8 a = p0[i], b = p1[i], c = p2[i], d = p3[i];
  float4 lo, hi;
  lo.x = (float)a[0] + (float)b[0] + (float)c[0] + (float)d[0];
  lo.y = (float)a[1] + (float)b[1] + (float)c[1] + (float)d[1];
  lo.z = (float)a[2] + (float)b[2] + (float)c[2] + (float)d[2];
  lo.w = (float)a[3] + (float)b[3] + (float)c[3] + (float)d[3];
  hi.x = (float)a[4] + (float)b[4] + (float)c[4] + (float)d[4];
  hi.y = (float)a[5] + (float)b[5] + (float)c[5] + (float)d[5];
  hi.z = (float)a[6] + (float)b[6] + (float)c[6] + (float)d[6];
  hi.w = (float)a[7] + (float)b[7] + (float)c[7] + (float)d[7];
  reinterpret_cast<float4*>(out)[i * 2] = lo;
  reinterpret_cast<float4*>(out)[i * 2 + 1] = hi;
}

// ---------------- row softmax: one wave per row ----------------
__global__ __launch_bounds__(256) void softmax_kernel(const ushort* __restrict__ S,
                                                      ushort* __restrict__ P) {
  const int wave = threadIdx.x >> 6, lane = threadIdx.x & 63;
  const int row = blockIdx.x * 4 + wave;
  const ushort* s = S + (size_t)row * SEQ;
  float v[64];
#pragma unroll
  for (int i = 0; i < 8; i++) {
    f16x8 h = reinterpret_cast<const f16x8*>(s)[i * 64 + lane];
#pragma unroll
    for (int j = 0; j < 8; j++) v[i * 8 + j] = (float)h[j];
  }
  float m = v[0];
#pragma unroll
  for (int j = 1; j < 64; j++) m = fmaxf(m, v[j]);
#pragma unroll
  for (int o = 32; o > 0; o >>= 1) m = fmaxf(m, __shfl_xor(m, o, 64));
  float sum = 0.f;
#pragma unroll
  for (int j = 0; j < 64; j++) {
    v[j] = __expf(v[j] - m);
    sum += v[j];
  }
#pragma unroll
  for (int o = 32; o > 0; o >>= 1) sum += __shfl_xor(sum, o, 64);
  float inv = 1.0f / sum;
  ushort* p = P + (size_t)row * SEQ;
#pragma unroll
  for (int i = 0; i < 8; i++) {
    f16x8 h;
#pragma unroll
    for (int j = 0; j < 8; j++) h[j] = (_Float16)(v[i * 8 + j] * inv);
    reinterpret_cast<f16x8*>(p)[i * 64 + lane] = h;
  }
}

extern "C" void kernel_launch(void* const* d_in, const int* in_sizes, int n_in,
                              void* d_out, int out_size, void* d_ws, size_t ws_size,
                              hipStream_t stream) {
  const float* X = (const float*)d_in[0];
  const float* Wk = (const float*)d_in[1];
  const float* Wv = (const float*)d_in[2];
  const float* Wq = (const float*)d_in[3];

  char* ws = (char*)d_ws;
  size_t off = 0;
  ushort* Xh = (ushort*)(ws + off); off += (size_t)SEQ * DIM * 2;      // 8 MB
  ushort* Wt = (ushort*)(ws + off); off += (size_t)3 * DIM * DIM * 2;  // 6 MB
  ushort* Kh = (ushort*)(ws + off); off += (size_t)SEQ * DIM * 2;      // 8 MB
  ushort* Qh = (ushort*)(ws + off); off += (size_t)SEQ * DIM * 2;      // 8 MB
  ushort* Vt = (ushort*)(ws + off); off += (size_t)SEQ * DIM * 2;      // 8 MB
  ushort* S = (ushort*)(ws + off);  off += (size_t)SEQ * SEQ * 2;      // 32 MB (reused as partials)
  ushort* P = (ushort*)(ws + off);  off += (size_t)SEQ * SEQ * 2;      // 32 MB

  ushort* Part = S;  // 4 x [SEQ,DIM] fp16 partials alias S; S dead after softmax

  convert_all_kernel<<<dim3(32, 32, 4), dim3(32, 8), 0, stream>>>(X, Wk, Wv, Wq, Xh, Wt);
  proj_kernel<<<dim3(256, 1, 3), 128, 0, stream>>>(Xh, Wt, Kh, Qh, Vt);
  score_kernel<<<1024, 128, 0, stream>>>(Kh, Qh, S);
  softmax_kernel<<<1024, 256, 0, stream>>>(S, P);
  out_splitk_kernel<<<1024, 128, 0, stream>>>(P, Vt, Part);
  reduce4_kernel<<<SEQ * DIM / 8 / 256, 256, 0, stream>>>(Part, (float*)d_out, SEQ * DIM / 8);
}

// Round 10
// 210.601 us; speedup vs baseline: 1.0231x; 1.0194x over previous
//
#include <hip/hip_runtime.h>
#include <hip/hip_fp16.h>
#include <cstdint>

#define SEQ 4096
#define DIM 1024

typedef _Float16 f16x8 __attribute__((ext_vector_type(8)));
typedef float f32x16 __attribute__((ext_vector_type(16)));
typedef __attribute__((address_space(1))) void as1_void;
typedef __attribute__((address_space(3))) void as3_void;

__device__ __forceinline__ ushort f2h(float f) {
  _Float16 h = (_Float16)f;
  return __builtin_bit_cast(ushort, h);
}

// ---------------- fused conversions: z<3 -> W transpose+cvt, z==3 -> X cvt ----------------
__global__ void convert_all_kernel(const float* __restrict__ X, const float* __restrict__ Wk,
                                   const float* __restrict__ Wv, const float* __restrict__ Wq,
                                   ushort* __restrict__ Xh, ushort* __restrict__ Wt) {
  const int z = blockIdx.z;
  const int tx = threadIdx.x, ty = threadIdx.y;  // (32,8)
  if (z == 3) {
    const int bid = blockIdx.y * 32 + blockIdx.x;
    const int t = ty * 32 + tx;
#pragma unroll
    for (int k = 0; k < 4; k++) {
      int i = bid * 1024 + k * 256 + t;
      float4 v = reinterpret_cast<const float4*>(X)[i];
      ushort4 o = { f2h(v.x), f2h(v.y), f2h(v.z), f2h(v.w) };
      reinterpret_cast<ushort4*>(Xh)[i] = o;
    }
    return;
  }
  __shared__ float tile[32][33];
  const float* W = (z == 0) ? Wk : (z == 1) ? Wv : Wq;
  int n0 = blockIdx.x * 32, k0 = blockIdx.y * 32;
#pragma unroll
  for (int r = 0; r < 4; r++) {
    int k = ty + r * 8;
    tile[k][tx] = W[(size_t)(k0 + k) * DIM + n0 + tx];
  }
  __syncthreads();
  ushort* out = Wt + (size_t)z * DIM * DIM;
#pragma unroll
  for (int r = 0; r < 4; r++) {
    int n = ty + r * 8;
    out[(size_t)(n0 + n) * DIM + k0 + tx] = f2h(tile[tx][n]);
  }
}

// ---------------- core GEMM tile A: 128x128 block, 64x64/wave (proj) ----------------
// XOR chunk swizzle key(r) = (r&7) ^ ((r>>3)&3); verified 0 bank conflicts (R4-R9).
template <bool F16_OUT>
__device__ __forceinline__ void gemm_tile(const ushort* __restrict__ A,
                                          const ushort* __restrict__ B,
                                          void* __restrict__ C,
                                          int N, int K, int m0, int n0,
                                          int kt0, int ktend) {
  constexpr int BK = 64;
  __shared__ __align__(16) ushort As[128 * BK];
  __shared__ __align__(16) ushort Bs[128 * BK];
  const int tid = threadIdx.x;
  const int wave = tid >> 6, lane = tid & 63;
  const int l31 = lane & 31, khalf = lane >> 5;
  const int wm = (wave & 1) * 64, wn = (wave >> 1) * 64;

  const int srow = tid >> 3;
  const int skey = ((srow & 7) ^ ((srow >> 3) & 3));
  const int sce = (((tid & 7) ^ skey) * 8);
  const int rk = (l31 & 7) ^ ((l31 >> 3) & 3);

  f32x16 acc[2][2];
#pragma unroll
  for (int i = 0; i < 2; i++)
#pragma unroll
    for (int j = 0; j < 2; j++)
#pragma unroll
      for (int r = 0; r < 16; r++) acc[i][j][r] = 0.f;

  for (int kt = kt0; kt < ktend; kt += BK) {
    __syncthreads();
#pragma unroll
    for (int q = 0; q < 4; q++) {
      const ushort* ga = A + (size_t)(m0 + srow + q * 32) * K + kt + sce;
      __builtin_amdgcn_global_load_lds((const as1_void*)ga,
                                       (as3_void*)&As[wave * 512 + q * 2048], 16, 0, 0);
    }
#pragma unroll
    for (int q = 0; q < 4; q++) {
      const ushort* gb = B + (size_t)(n0 + srow + q * 32) * K + kt + sce;
      __builtin_amdgcn_global_load_lds((const as1_void*)gb,
                                       (as3_void*)&Bs[wave * 512 + q * 2048], 16, 0, 0);
    }
    __syncthreads();
#pragma unroll
    for (int ks = 0; ks < 4; ks++) {
      f16x8 af[2], bfr[2];
      const int ck = (ks * 2 + khalf);
#pragma unroll
      for (int i = 0; i < 2; i++)
        af[i] = *reinterpret_cast<const f16x8*>(
            &As[(wm + i * 32 + l31) * BK + ((ck ^ rk) * 8)]);
#pragma unroll
      for (int j = 0; j < 2; j++)
        bfr[j] = *reinterpret_cast<const f16x8*>(
            &Bs[(wn + j * 32 + l31) * BK + ((ck ^ rk) * 8)]);
#pragma unroll
      for (int i = 0; i < 2; i++)
#pragma unroll
        for (int j = 0; j < 2; j++)
          acc[i][j] = __builtin_amdgcn_mfma_f32_32x32x16_f16(af[i], bfr[j], acc[i][j], 0, 0, 0);
    }
  }

  // epilogue: 32x32 C/D layout col=lane&31, row=(reg&3)+8*(reg>>2)+4*(lane>>5)  [m74/m101]
#pragma unroll
  for (int i = 0; i < 2; i++)
#pragma unroll
    for (int j = 0; j < 2; j++)
#pragma unroll
      for (int r = 0; r < 16; r++) {
        int row = m0 + wm + i * 32 + (r & 3) + 8 * (r >> 2) + 4 * khalf;
        int col = n0 + wn + j * 32 + l31;
        if (F16_OUT)
          reinterpret_cast<ushort*>(C)[(size_t)row * N + col] = f2h(acc[i][j][r]);
        else
          reinterpret_cast<float*>(C)[(size_t)row * N + col] = acc[i][j][r];
      }
}

// ---------------- core GEMM tile B: 128x256 block, 64x128/wave (score/out) ----------------
// 32 MFMA per wave per barrier-pair; 48KB LDS, 2 blocks/CU — best-measured point (R6: 203 µs).
__device__ __forceinline__ void gemm_tile_w128(const ushort* __restrict__ A,
                                               const ushort* __restrict__ B,
                                               ushort* __restrict__ C,
                                               int N, int K, int m0, int n0,
                                               int kt0, int ktend) {
  constexpr int BK = 64;
  __shared__ __align__(16) ushort As[128 * BK];   // 16 KB
  __shared__ __align__(16) ushort Bs[256 * BK];   // 32 KB
  const int tid = threadIdx.x;
  const int wave = tid >> 6, lane = tid & 63;
  const int l31 = lane & 31, khalf = lane >> 5;
  const int wm = (wave & 1) * 64, wn = (wave >> 1) * 128;

  const int srow = tid >> 3;
  const int skey = ((srow & 7) ^ ((srow >> 3) & 3));
  const int sce = (((tid & 7) ^ skey) * 8);
  const int rk = (l31 & 7) ^ ((l31 >> 3) & 3);

  f32x16 acc[2][4];
#pragma unroll
  for (int i = 0; i < 2; i++)
#pragma unroll
    for (int j = 0; j < 4; j++)
#pragma unroll
      for (int r = 0; r < 16; r++) acc[i][j][r] = 0.f;

  for (int kt = kt0; kt < ktend; kt += BK) {
    __syncthreads();
#pragma unroll
    for (int q = 0; q < 4; q++) {
      const ushort* ga = A + (size_t)(m0 + srow + q * 32) * K + kt + sce;
      __builtin_amdgcn_global_load_lds((const as1_void*)ga,
                                       (as3_void*)&As[wave * 512 + q * 2048], 16, 0, 0);
    }
#pragma unroll
    for (int q = 0; q < 8; q++) {
      const ushort* gb = B + (size_t)(n0 + srow + q * 32) * K + kt + sce;
      __builtin_amdgcn_global_load_lds((const as1_void*)gb,
                                       (as3_void*)&Bs[wave * 512 + q * 2048], 16, 0, 0);
    }
    __syncthreads();
#pragma unroll
    for (int ks = 0; ks < 4; ks++) {
      f16x8 af[2], bfr[4];
      const int ck = (ks * 2 + khalf);
#pragma unroll
      for (int i = 0; i < 2; i++)
        af[i] = *reinterpret_cast<const f16x8*>(
            &As[(wm + i * 32 + l31) * BK + ((ck ^ rk) * 8)]);
#pragma unroll
      for (int j = 0; j < 4; j++)
        bfr[j] = *reinterpret_cast<const f16x8*>(
            &Bs[(wn + j * 32 + l31) * BK + ((ck ^ rk) * 8)]);
#pragma unroll
      for (int i = 0; i < 2; i++)
#pragma unroll
        for (int j = 0; j < 4; j++)
          acc[i][j] = __builtin_amdgcn_mfma_f32_32x32x16_f16(af[i], bfr[j], acc[i][j], 0, 0, 0);
    }
  }

#pragma unroll
  for (int i = 0; i < 2; i++)
#pragma unroll
    for (int j = 0; j < 4; j++)
#pragma unroll
      for (int r = 0; r < 16; r++) {
        int row = m0 + wm + i * 32 + (r & 3) + 8 * (r >> 2) + 4 * khalf;
        int col = n0 + wn + j * 32 + l31;
        C[(size_t)row * N + col] = f2h(acc[i][j][r]);
      }
}

// ---------------- fused K/Q/V^T projections (768 blocks, tile A) ----------------
__global__ __launch_bounds__(256) void proj_kernel(const ushort* __restrict__ Xh,
                                                   const ushort* __restrict__ Wt,
                                                   ushort* __restrict__ Kh,
                                                   ushort* __restrict__ Qh,
                                                   ushort* __restrict__ Vt) {
  const int z = blockIdx.z;
  const ushort* A;
  const ushort* B;
  ushort* C;
  int N, m0, n0;
  if (z < 2) {
    A = Xh;
    B = Wt + (size_t)(z == 0 ? 0 : 2) * DIM * DIM;
    C = (z == 0) ? Kh : Qh;
    N = DIM;
    m0 = (blockIdx.x >> 3) * 128;
    n0 = (blockIdx.x & 7) * 128;
  } else {
    A = Wt + (size_t)DIM * DIM;
    B = Xh;
    C = Vt;
    N = SEQ;
    m0 = (blockIdx.x >> 5) * 128;
    n0 = (blockIdx.x & 31) * 128;
  }
  gemm_tile<true>(A, B, C, N, DIM, m0, n0, 0, DIM);
}

// ---------------- S = K @ Q^T (fp16), 128x256 tiles, XCD-swizzled ----------------
__global__ __launch_bounds__(256, 2) void score_kernel(const ushort* __restrict__ Kh,
                                                       const ushort* __restrict__ Qh,
                                                       ushort* __restrict__ S) {
  const int f = blockIdx.x;          // [0,512)
  const int xcd = f & 7;
  const int r = f >> 3;              // [0,64)
  const int t = xcd * 64 + r;        // XCD-contiguous
  const int within = t & 63, st = t >> 6;   // 8x8 supertile, st in [0,8)
  const int sx = within & 7, sy = within >> 3;
  const int tx = (st & 1) * 8 + sx;  // n-tile [0,16)
  const int ty = (st >> 1) * 8 + sy; // m-tile [0,32)
  gemm_tile_w128(Kh, Qh, S, SEQ, DIM, ty * 128, tx * 256, 0, DIM);
}

// ---------------- O partials: split-K=4, 128x256 tiles, fp16, XCD-swizzled ----------------
__global__ __launch_bounds__(256, 2) void out_splitk_kernel(const ushort* __restrict__ P,
                                                            const ushort* __restrict__ Vt,
                                                            ushort* __restrict__ Part) {
  const int f = blockIdx.x;          // [0,512)
  const int z = f >> 7;              // split slice
  const int q = f & 127;
  const int xcd = q & 7;
  const int r = q >> 3;              // [0,16)
  const int t = xcd * 16 + r;        // [0,128)
  const int tx = t & 3, ty = t >> 2; // n-tile [0,4), m-tile [0,32)
  ushort* C = Part + (size_t)z * SEQ * DIM;
  gemm_tile_w128(P, Vt, C, DIM, SEQ, ty * 128, tx * 256,
                 z * (SEQ / 4), (z + 1) * (SEQ / 4));
}

__global__ void reduce4_kernel(const ushort* __restrict__ Part, float* __restrict__ out, int n8) {
  int i = blockIdx.x * blockDim.x + threadIdx.x;
  if (i >= n8) return;
  const f16x8* p0 = reinterpret_cast<const f16x8*>(Part);
  const f16x8* p1 = p0 + n8;
  const f16x8* p2 = p1 + n8;
  const f16x8* p3 = p2 + n8;
  f16x8 a = p0[i], b = p1[i], c = p2[i], d = p3[i];
  float4 lo, hi;
  lo.x = (float)a[0] + (float)b[0] + (float)c[0] + (float)d[0];
  lo.y = (float)a[1] + (float)b[1] + (float)c[1] + (float)d[1];
  lo.z = (float)a[2] + (float)b[2] + (float)c[2] + (float)d[2];
  lo.w = (float)a[3] + (float)b[3] + (float)c[3] + (float)d[3];
  hi.x = (float)a[4] + (float)b[4] + (float)c[4] + (float)d[4];
  hi.y = (float)a[5] + (float)b[5] + (float)c[5] + (float)d[5];
  hi.z = (float)a[6] + (float)b[6] + (float)c[6] + (float)d[6];
  hi.w = (float)a[7] + (float)b[7] + (float)c[7] + (float)d[7];
  reinterpret_cast<float4*>(out)[i * 2] = lo;
  reinterpret_cast<float4*>(out)[i * 2 + 1] = hi;
}

// ---------------- row softmax: one wave per row ----------------
__global__ __launch_bounds__(256) void softmax_kernel(const ushort* __restrict__ S,
                                                      ushort* __restrict__ P) {
  const int wave = threadIdx.x >> 6, lane = threadIdx.x & 63;
  const int row = blockIdx.x * 4 + wave;
  const ushort* s = S + (size_t)row * SEQ;
  float v[64];
#pragma unroll
  for (int i = 0; i < 8; i++) {
    f16x8 h = reinterpret_cast<const f16x8*>(s)[i * 64 + lane];
#pragma unroll
    for (int j = 0; j < 8; j++) v[i * 8 + j] = (float)h[j];
  }
  float m = v[0];
#pragma unroll
  for (int j = 1; j < 64; j++) m = fmaxf(m, v[j]);
#pragma unroll
  for (int o = 32; o > 0; o >>= 1) m = fmaxf(m, __shfl_xor(m, o, 64));
  float sum = 0.f;
#pragma unroll
  for (int j = 0; j < 64; j++) {
    v[j] = __expf(v[j] - m);
    sum += v[j];
  }
#pragma unroll
  for (int o = 32; o > 0; o >>= 1) sum += __shfl_xor(sum, o, 64);
  float inv = 1.0f / sum;
  ushort* p = P + (size_t)row * SEQ;
#pragma unroll
  for (int i = 0; i < 8; i++) {
    f16x8 h;
#pragma unroll
    for (int j = 0; j < 8; j++) h[j] = (_Float16)(v[i * 8 + j] * inv);
    reinterpret_cast<f16x8*>(p)[i * 64 + lane] = h;
  }
}

extern "C" void kernel_launch(void* const* d_in, const int* in_sizes, int n_in,
                              void* d_out, int out_size, void* d_ws, size_t ws_size,
                              hipStream_t stream) {
  const float* X = (const float*)d_in[0];
  const float* Wk = (const float*)d_in[1];
  const float* Wv = (const float*)d_in[2];
  const float* Wq = (const float*)d_in[3];

  char* ws = (char*)d_ws;
  size_t off = 0;
  ushort* Xh = (ushort*)(ws + off); off += (size_t)SEQ * DIM * 2;      // 8 MB
  ushort* Wt = (ushort*)(ws + off); off += (size_t)3 * DIM * DIM * 2;  // 6 MB
  ushort* Kh = (ushort*)(ws + off); off += (size_t)SEQ * DIM * 2;      // 8 MB
  ushort* Qh = (ushort*)(ws + off); off += (size_t)SEQ * DIM * 2;      // 8 MB
  ushort* Vt = (ushort*)(ws + off); off += (size_t)SEQ * DIM * 2;      // 8 MB
  ushort* S = (ushort*)(ws + off);  off += (size_t)SEQ * SEQ * 2;      // 32 MB (reused as partials)
  ushort* P = (ushort*)(ws + off);  off += (size_t)SEQ * SEQ * 2;      // 32 MB

  ushort* Part = S;  // 4 x [SEQ,DIM] fp16 partials alias S; S dead after softmax

  convert_all_kernel<<<dim3(32, 32, 4), dim3(32, 8), 0, stream>>>(X, Wk, Wv, Wq, Xh, Wt);
  proj_kernel<<<dim3(256, 1, 3), 256, 0, stream>>>(Xh, Wt, Kh, Qh, Vt);
  score_kernel<<<512, 256, 0, stream>>>(Kh, Qh, S);
  softmax_kernel<<<1024, 256, 0, stream>>>(S, P);
  out_splitk_kernel<<<512, 256, 0, stream>>>(P, Vt, Part);
  reduce4_kernel<<<SEQ * DIM / 8 / 256, 256, 0, stream>>>(Part, (float*)d_out, SEQ * DIM / 8);
}